// Round 5
// baseline (827.206 us; speedup 1.0000x reference)
//
#include <hip/hip_runtime.h>
#include <hip/hip_bf16.h>
#include <math.h>

typedef __attribute__((ext_vector_type(8))) __bf16 bf16x8;
typedef __attribute__((ext_vector_type(4))) float floatx4;

__device__ inline unsigned short f2u(float f) {
  __hip_bfloat16 h = __float2bfloat16(f);
  unsigned short u;
  __builtin_memcpy(&u, &h, 2);
  return u;
}

__device__ inline floatx4 mfma16(bf16x8 a, bf16x8 b, floatx4 c) {
  return __builtin_amdgcn_mfma_f32_16x16x32_bf16(a, b, c, 0, 0, 0);
}

__device__ inline void gload_lds16(const unsigned short* g, unsigned short* l) {
  __builtin_amdgcn_global_load_lds(
      (__attribute__((address_space(1))) void*)g,
      (__attribute__((address_space(3))) void*)l,
      16, 0, 0);
}

// ---------------- cast fp32 -> bf16 (vectorized, optional scale) ----------------
__global__ __launch_bounds__(256) void castk(const float* __restrict__ in,
                                             unsigned short* __restrict__ out,
                                             int n4, float scale) {
  int i = blockIdx.x * 256 + threadIdx.x;
  if (i >= n4) return;
  const float4 v = reinterpret_cast<const float4*>(in)[i];
  ushort4 o;
  o.x = f2u(v.x * scale);
  o.y = f2u(v.y * scale);
  o.z = f2u(v.z * scale);
  o.w = f2u(v.w * scale);
  reinterpret_cast<ushort4*>(out)[i] = o;
}

// ---------------- GEMM: C[m,n] = sum_k A[m,k] * B[n,k] ----
template <int OUT>
__global__ __launch_bounds__(256)
void gemm_bt(const unsigned short* __restrict__ A,
             const unsigned short* __restrict__ B,
             unsigned short* __restrict__ Cb,
             float* __restrict__ Cf,
             const float* __restrict__ bias,
             int M, int N, int K) {
  __shared__ unsigned short Asm_[128 * 32];
  __shared__ unsigned short Bsm_[128 * 32];
  const int t = threadIdx.x;
  const int w = t >> 6;
  const int l = t & 63;
  const int m0 = blockIdx.y * 128;
  const int n0 = blockIdx.x * 128;
  const int wm = w >> 1, wn = w & 1;

  const int srow = l >> 2;
  const int scol = (l & 3) * 8;
  const unsigned short* gA = A + (size_t)(m0 + w * 32 + srow) * K + scol;
  const unsigned short* gB = B + (size_t)(n0 + w * 32 + srow) * K + scol;
  unsigned short* lA = &Asm_[w * 1024];
  unsigned short* lB = &Bsm_[w * 1024];

  floatx4 acc[4][4];
#pragma unroll
  for (int i = 0; i < 4; i++)
#pragma unroll
    for (int j = 0; j < 4; j++) acc[i][j] = (floatx4){0.f, 0.f, 0.f, 0.f};

  const int fr = l & 15;
  const int fk = (l >> 4) * 8;

  for (int k0 = 0; k0 < K; k0 += 32) {
    gload_lds16(gA + k0, lA);
    gload_lds16(gA + (size_t)16 * K + k0, lA + 512);
    gload_lds16(gB + k0, lB);
    gload_lds16(gB + (size_t)16 * K + k0, lB + 512);
    __syncthreads();

    bf16x8 af[4], bfr[4];
#pragma unroll
    for (int i = 0; i < 4; i++)
      af[i] = *reinterpret_cast<const bf16x8*>(&Asm_[(wm * 64 + i * 16 + fr) * 32 + fk]);
#pragma unroll
    for (int j = 0; j < 4; j++)
      bfr[j] = *reinterpret_cast<const bf16x8*>(&Bsm_[(wn * 64 + j * 16 + fr) * 32 + fk]);
#pragma unroll
    for (int i = 0; i < 4; i++)
#pragma unroll
      for (int j = 0; j < 4; j++) acc[i][j] = mfma16(af[i], bfr[j], acc[i][j]);
    __syncthreads();
  }

  const int er = (l >> 4) * 4;
  const int ec = l & 15;
#pragma unroll
  for (int i = 0; i < 4; i++) {
#pragma unroll
    for (int j = 0; j < 4; j++) {
      const int col = n0 + wn * 64 + j * 16 + ec;
      if (OUT == 2) {
        const int hv = col >> 7, dh = col & 127;
        const int row0 = m0 + wm * 64 + i * 16 + er;
        const int bb = row0 >> 11;
        const int t0 = row0 & 2047;
        unsigned short* vp =
            Cb + (((size_t)(bb * 16 + hv)) * 128 + dh) * 2048 + t0;
#pragma unroll
        for (int r = 0; r < 4; r++) vp[r] = f2u(acc[i][j][r]);
      } else {
#pragma unroll
        for (int r = 0; r < 4; r++) {
          const int row = m0 + wm * 64 + i * 16 + er + r;
          if (OUT == 1) {
            Cf[(size_t)row * N + col] = acc[i][j][r] + bias[col];
          } else {
            Cb[(size_t)row * N + col] = f2u(acc[i][j][r]);
          }
        }
      }
    }
  }
}

// ---------------- flash attention ----------------
// Y2: (8192 x 4096) bf16, cols [0,2048)=Q (pre-scaled), [2048,4096)=K.
// Vtg: [64 bh][128 dh][2048 t] bf16 (V transposed per head).
// Block: 4 waves x 32 q-rows = 128 q-rows. KV tile = 64.
// K and V each SINGLE-buffered (50.9 KB LDS -> 3 blocks/CU); each stage issued
// right after the barrier retiring its readers, consumed after the next
// barrier's vmcnt drain. 2 barriers/iter. setprio around MFMA clusters (T5).
__global__ __launch_bounds__(256, 3)
void attn_kernel(const unsigned short* __restrict__ Y2,
                 const unsigned short* __restrict__ Vtg,
                 unsigned short* __restrict__ att) {
  __shared__ unsigned short Kt[64 * 128];   // 16 KB, [kvrow][dh] swizzled
  __shared__ unsigned short Vt[128 * 64];   // 16 KB, [dh][kv] swizzled
  __shared__ unsigned short Pl[4][32 * 72]; // 18 KB, per-wave P, stride 72

  const int t = threadIdx.x;
  const int w = t >> 6;
  const int l = t & 63;
  const int bid = blockIdx.x;
  const int bh = bid & 63;
  const int qt = bid >> 6;  // 0..15, 128 q-rows each
  const int b = bh >> 4;
  const int h = bh & 15;

  const size_t ybase = (size_t)b * 2048 * 4096 + (size_t)h * 128;
  const unsigned short* Qp = Y2 + ybase;
  const unsigned short* Kp = Y2 + ybase + 2048;
  const unsigned short* Vp = Vtg + (size_t)bh * 128 * 2048;

  const int fr = l & 15;
  const int fkb = l >> 4;
  const int key = fr & 7;  // read-side swizzle key (row & 7)

  // K staging: call c covers rows c*16 + (t>>4), dest slot t&15 (of 16).
  // Stored slot s holds logical slot s ^ (row&7); row&7 = (t>>4)&7.
  const int ksr = t >> 4;
  const int ksl = (t & 15) ^ (ksr & 7);
  const unsigned short* Ksrc = Kp + (size_t)ksr * 4096 + ksl * 8;

  // V staging: call c covers rows c*32 + (t>>3), dest slot t&7 (of 8).
  const int vsr = t >> 3;
  const int vsl = (t & 7) ^ (vsr & 7);
  const unsigned short* Vsrc = Vp + (size_t)vsr * 2048 + vsl * 8;

  // Q fragments: rows qt*128 + w*32 + i*16 + fr
  bf16x8 qf[2][4];
#pragma unroll
  for (int i = 0; i < 2; i++)
#pragma unroll
    for (int kk = 0; kk < 4; kk++)
      qf[i][kk] = *reinterpret_cast<const bf16x8*>(
          &Qp[(size_t)(qt * 128 + w * 32 + i * 16 + fr) * 4096 + kk * 32 + fkb * 8]);

  floatx4 oacc[2][8];
#pragma unroll
  for (int i = 0; i < 2; i++)
#pragma unroll
    for (int nt = 0; nt < 8; nt++) oacc[i][nt] = (floatx4){0.f, 0.f, 0.f, 0.f};
  float mrun[2][4], lrun[2][4];
#pragma unroll
  for (int i = 0; i < 2; i++)
#pragma unroll
    for (int r = 0; r < 4; r++) {
      mrun[i][r] = -INFINITY;
      lrun[i][r] = 0.f;
    }

  unsigned short* Pw = &Pl[w][0];

  // prologue: stage K(0) and V(0)
#pragma unroll
  for (int c = 0; c < 4; c++)
    gload_lds16(Ksrc + (size_t)c * 16 * 4096, &Kt[c * 2048 + w * 512]);
#pragma unroll
  for (int c = 0; c < 4; c++)
    gload_lds16(Vsrc + (size_t)c * 32 * 2048, &Vt[c * 2048 + w * 512]);
  __syncthreads();  // vmcnt drained: K(0), V(0) ready

  for (int kv = 0; kv < 2048; kv += 64) {
    // ---- QK^T: 32 q-rows x 64 kv from Kt ----
    floatx4 sacc[2][4];
#pragma unroll
    for (int i = 0; i < 2; i++)
#pragma unroll
      for (int nt = 0; nt < 4; nt++) sacc[i][nt] = (floatx4){0.f, 0.f, 0.f, 0.f};
    __builtin_amdgcn_s_setprio(1);
#pragma unroll
    for (int nt = 0; nt < 4; nt++) {
#pragma unroll
      for (int kk = 0; kk < 4; kk++) {
        bf16x8 kf = *reinterpret_cast<const bf16x8*>(
            &Kt[((nt * 16 + fr) * 16 + ((kk * 4 + fkb) ^ key)) * 8]);
        sacc[0][nt] = mfma16(qf[0][kk], kf, sacc[0][nt]);
        sacc[1][nt] = mfma16(qf[1][kk], kf, sacc[1][nt]);
      }
    }
    __builtin_amdgcn_s_setprio(0);

    // ---- online softmax with defer-max (THR=8); q-row-in-16 = fkb*4+r ----
#pragma unroll
    for (int i = 0; i < 2; i++) {
#pragma unroll
      for (int r = 0; r < 4; r++) {
        float s0 = sacc[i][0][r], s1 = sacc[i][1][r];
        float s2 = sacc[i][2][r], s3 = sacc[i][3][r];
        float mx = fmaxf(fmaxf(s0, s1), fmaxf(s2, s3));
        mx = fmaxf(mx, __shfl_xor(mx, 1));
        mx = fmaxf(mx, __shfl_xor(mx, 2));
        mx = fmaxf(mx, __shfl_xor(mx, 4));
        mx = fmaxf(mx, __shfl_xor(mx, 8));
        if (mx > mrun[i][r] + 8.0f) {
          float alpha = __expf(mrun[i][r] - mx);
          mrun[i][r] = mx;
          lrun[i][r] *= alpha;
#pragma unroll
          for (int nt = 0; nt < 8; nt++) oacc[i][nt][r] *= alpha;
        }
        const float m = mrun[i][r];
        float p0 = __expf(s0 - m);
        float p1 = __expf(s1 - m);
        float p2 = __expf(s2 - m);
        float p3 = __expf(s3 - m);
        float ps = (p0 + p1) + (p2 + p3);
        ps += __shfl_xor(ps, 1);
        ps += __shfl_xor(ps, 2);
        ps += __shfl_xor(ps, 4);
        ps += __shfl_xor(ps, 8);
        lrun[i][r] += ps;
        const int pr = i * 16 + fkb * 4 + r;
        Pw[pr * 72 + fr] = f2u(p0);
        Pw[pr * 72 + 16 + fr] = f2u(p1);
        Pw[pr * 72 + 32 + fr] = f2u(p2);
        Pw[pr * 72 + 48 + fr] = f2u(p3);
      }
    }

    __syncthreads();  // bar1: all Kt reads done; V(kv) landed long ago

    // ---- stage K(kv+64) into Kt; latency hides under PV ----
    if (kv + 64 < 2048) {
#pragma unroll
      for (int c = 0; c < 4; c++)
        gload_lds16(Ksrc + (size_t)(kv + 64 + c * 16) * 4096,
                    &Kt[c * 2048 + w * 512]);
    }

    // ---- PV: out(32x128) += P(32x64) @ V(64x128) ----
    bf16x8 pf[2][2];
#pragma unroll
    for (int i = 0; i < 2; i++) {
      pf[i][0] = *reinterpret_cast<const bf16x8*>(&Pw[(i * 16 + fr) * 72 + fkb * 8]);
      pf[i][1] = *reinterpret_cast<const bf16x8*>(&Pw[(i * 16 + fr) * 72 + 32 + fkb * 8]);
    }
    __builtin_amdgcn_s_setprio(1);
#pragma unroll
    for (int nt = 0; nt < 8; nt++) {
      const unsigned short* vr = &Vt[(nt * 16 + fr) * 64];
      bf16x8 vf0 = *reinterpret_cast<const bf16x8*>(vr + (fkb ^ key) * 8);
      bf16x8 vf1 = *reinterpret_cast<const bf16x8*>(vr + ((fkb + 4) ^ key) * 8);
#pragma unroll
      for (int i = 0; i < 2; i++) {
        oacc[i][nt] = mfma16(pf[i][0], vf0, oacc[i][nt]);
        oacc[i][nt] = mfma16(pf[i][1], vf1, oacc[i][nt]);
      }
    }
    __builtin_amdgcn_s_setprio(0);

    __syncthreads();  // bar2: all Vt reads done; K(kv+64) drained

    // ---- stage V(kv+64) into Vt; latency hides under next QK^T+softmax ----
    if (kv + 64 < 2048) {
#pragma unroll
      for (int c = 0; c < 4; c++)
        gload_lds16(Vsrc + (size_t)c * 32 * 2048 + (kv + 64),
                    &Vt[c * 2048 + w * 512]);
    }
  }

  // ---- epilogue ----
#pragma unroll
  for (int i = 0; i < 2; i++) {
#pragma unroll
    for (int r = 0; r < 4; r++) {
      const float inv = 1.0f / lrun[i][r];
      const int row = qt * 128 + w * 32 + i * 16 + fkb * 4 + r;
      unsigned short* op = att + ((size_t)b * 2048 + row) * 2048 + h * 128 + fr;
#pragma unroll
      for (int nt = 0; nt < 8; nt++) op[nt * 16] = f2u(oacc[i][nt][r] * inv);
    }
  }
}

// ---------------- launch ----------------
extern "C" void kernel_launch(void* const* d_in, const int* in_sizes, int n_in,
                              void* d_out, int out_size, void* d_ws, size_t ws_size,
                              hipStream_t stream) {
  const float* x = (const float*)d_in[0];
  const float* wq = (const float*)d_in[1];
  const float* wk = (const float*)d_in[2];
  const float* wv = (const float*)d_in[3];
  const float* wo = (const float*)d_in[4];
  const float* bo = (const float*)d_in[5];

  unsigned short* ws = (unsigned short*)d_ws;
  unsigned short* x16 = ws;                      // 16,777,216
  unsigned short* wqkv16 = x16 + 16777216;       // 12,582,912
  unsigned short* wo16 = wqkv16 + 12582912;      // 4,194,304
  unsigned short* Y2 = wo16 + 4194304;           // 33,554,432 (8192 x 4096, Q|K)
  unsigned short* Vtg = Y2 + 33554432;           // 16,777,216 (64 x 128 x 2048)
  unsigned short* att16 = Vtg + 16777216;        // 16,777,216
  // total 100,663,296 ushorts = 201.3 MB

  const float sscale = 0.08838834764831845f;  // 1/sqrt(128), folded into wq

  castk<<<16384, 256, 0, stream>>>(x, x16, 4194304, 1.0f);
  castk<<<4096, 256, 0, stream>>>(wq, wqkv16, 1048576, sscale);
  castk<<<4096, 256, 0, stream>>>(wk, wqkv16 + 4194304, 1048576, 1.0f);
  castk<<<4096, 256, 0, stream>>>(wv, wqkv16 + 8388608, 1048576, 1.0f);
  castk<<<4096, 256, 0, stream>>>(wo, wo16, 1048576, 1.0f);

  // Q,K projections -> Y2 (row-major)
  dim3 gqk(32, 64);
  gemm_bt<0><<<gqk, 256, 0, stream>>>(x16, wqkv16, Y2, nullptr, nullptr,
                                      8192, 4096, 2048);
  // V projection -> Vtg (transposed per head)
  dim3 gv(16, 64);
  gemm_bt<2><<<gv, 256, 0, stream>>>(x16, wqkv16 + 8388608, Vtg, nullptr,
                                     nullptr, 8192, 2048, 2048);

  attn_kernel<<<1024, 256, 0, stream>>>(Y2, Vtg, att16);

  dim3 go(16, 64);
  gemm_bt<1><<<go, 256, 0, stream>>>(att16, wo16, nullptr, (float*)d_out, bo,
                                     8192, 2048, 2048);
}

// Round 6
// 556.811 us; speedup vs baseline: 1.4856x; 1.4856x over previous
//
#include <hip/hip_runtime.h>
#include <hip/hip_bf16.h>
#include <math.h>

typedef __attribute__((ext_vector_type(8))) __bf16 bf16x8;
typedef __attribute__((ext_vector_type(4))) float floatx4;

__device__ inline unsigned short f2u(float f) {
  __hip_bfloat16 h = __float2bfloat16(f);
  unsigned short u;
  __builtin_memcpy(&u, &h, 2);
  return u;
}

__device__ inline floatx4 mfma16(bf16x8 a, bf16x8 b, floatx4 c) {
  return __builtin_amdgcn_mfma_f32_16x16x32_bf16(a, b, c, 0, 0, 0);
}

__device__ inline void gload_lds16(const unsigned short* g, unsigned short* l) {
  __builtin_amdgcn_global_load_lds(
      (__attribute__((address_space(1))) void*)g,
      (__attribute__((address_space(3))) void*)l,
      16, 0, 0);
}

// ---------------- cast fp32 -> bf16 (vectorized, optional scale) ----------------
__global__ __launch_bounds__(256) void castk(const float* __restrict__ in,
                                             unsigned short* __restrict__ out,
                                             int n4, float scale) {
  int i = blockIdx.x * 256 + threadIdx.x;
  if (i >= n4) return;
  const float4 v = reinterpret_cast<const float4*>(in)[i];
  ushort4 o;
  o.x = f2u(v.x * scale);
  o.y = f2u(v.y * scale);
  o.z = f2u(v.z * scale);
  o.w = f2u(v.w * scale);
  reinterpret_cast<ushort4*>(out)[i] = o;
}

// ---------------- 256x256 8-phase GEMM: C[m,n] = sum_k A[m,k]*B[n,k] ----------
// 8 waves (2M x 4N), BK=64, 128KB dynamic LDS (A dbuf 64KB + B dbuf 64KB),
// 4 phases/K-tile, counted vmcnt(4) once per tile, raw s_barrier, setprio.
// LDS swizzle: 16B slot ^ (row&7) within each 128B row (inverse-swz source,
// swz read). OUT: 0 = bf16 row-major, 1 = f32 + bias, 2 = bf16 V-transposed.
template <int OUT>
__global__ __launch_bounds__(512, 2)
void gemm256(const unsigned short* __restrict__ A,
             const unsigned short* __restrict__ B,
             unsigned short* __restrict__ Cb,
             float* __restrict__ Cf,
             const float* __restrict__ bias,
             int M, int N, int K) {
  extern __shared__ unsigned short lds[];  // [0,16384)=A buf0, [16384,32768)=A buf1
                                           // [32768,49152)=B buf0, [49152,65536)=B buf1 (ushort idx)
  const int t = threadIdx.x;
  const int w = t >> 6;
  const int l = t & 63;
  const int wm = w >> 2;   // 0..1
  const int wn = w & 3;    // 0..3
  const int fr = l & 15;
  const int fkb = l >> 4;
  const int key = fr & 7;
  const int sslot = (l & 7) ^ (l >> 3);  // stage source slot (row-key = l>>3)

  const int m0 = blockIdx.y * 256;
  const int n0 = blockIdx.x * 256;
  const int T = K >> 6;

  // stage half-tile h (128 rows) of tile kt2 from G (row base rb) into ldsbase
  auto stage = [&](const unsigned short* G, int rb, int kt2, int h, int ldsbase) {
    const int d2 = kt2 & 1;
    const int rt = h * 128 + w * 16 + (l >> 3);
    const unsigned short* s0 = G + (size_t)(rb + rt) * K + kt2 * 64 + sslot * 8;
    unsigned short* dst = lds + ldsbase + d2 * 16384 + h * 8192 + w * 1024;
    gload_lds16(s0, dst);                       // rows rt..(+8 stride over lanes)
    gload_lds16(s0 + (size_t)8 * K, dst + 512); // rows rt+8
  };

  floatx4 acc[8][4];
#pragma unroll
  for (int m = 0; m < 8; m++)
#pragma unroll
    for (int n = 0; n < 4; n++) acc[m][n] = (floatx4){0.f, 0.f, 0.f, 0.f};

  // ---- prologue: A(0), B(0), B(1); drain A0+B0, keep B1 in flight ----
  stage(A, m0, 0, 0, 0);
  stage(A, m0, 0, 1, 0);
  stage(B, n0, 0, 0, 32768);
  stage(B, n0, 0, 1, 32768);
  if (1 < T) {
    stage(B, n0, 1, 0, 32768);
    stage(B, n0, 1, 1, 32768);
    asm volatile("s_waitcnt vmcnt(4)" ::: "memory");
  } else {
    asm volatile("s_waitcnt vmcnt(0)" ::: "memory");
  }
  __builtin_amdgcn_s_barrier();

#define GPHASE(q, STAGE_STMT)                                               \
  {                                                                         \
    bf16x8 a00 = *reinterpret_cast<const bf16x8*>(                          \
        Ab + (wm * 128 + (2 * (q)) * 16 + fr) * 64 + ((fkb ^ key)) * 8);    \
    bf16x8 a01 = *reinterpret_cast<const bf16x8*>(                          \
        Ab + (wm * 128 + (2 * (q)) * 16 + fr) * 64 + (((4 + fkb) ^ key)) * 8); \
    bf16x8 a10 = *reinterpret_cast<const bf16x8*>(                          \
        Ab + (wm * 128 + (2 * (q) + 1) * 16 + fr) * 64 + ((fkb ^ key)) * 8);\
    bf16x8 a11 = *reinterpret_cast<const bf16x8*>(                          \
        Ab + (wm * 128 + (2 * (q) + 1) * 16 + fr) * 64 + (((4 + fkb) ^ key)) * 8); \
    STAGE_STMT;                                                             \
    __builtin_amdgcn_s_barrier();                                           \
    asm volatile("s_waitcnt lgkmcnt(0)");                                   \
    __builtin_amdgcn_s_setprio(1);                                          \
    _Pragma("unroll")                                                       \
    for (int n = 0; n < 4; n++) {                                           \
      acc[2 * (q)][n] = mfma16(a00, bfr[0][n], acc[2 * (q)][n]);            \
      acc[2 * (q)][n] = mfma16(a01, bfr[1][n], acc[2 * (q)][n]);            \
      acc[2 * (q) + 1][n] = mfma16(a10, bfr[0][n], acc[2 * (q) + 1][n]);    \
      acc[2 * (q) + 1][n] = mfma16(a11, bfr[1][n], acc[2 * (q) + 1][n]);    \
    }                                                                       \
    __builtin_amdgcn_s_setprio(0);                                          \
    __builtin_amdgcn_s_barrier();                                           \
  }

  for (int kt = 0; kt < T; ++kt) {
    const int d = kt & 1;
    const unsigned short* Ab = lds + d * 16384;
    const unsigned short* Bb = lds + 32768 + d * 16384;

    bf16x8 bfr[2][4];
#pragma unroll
    for (int kk = 0; kk < 2; kk++)
#pragma unroll
      for (int n = 0; n < 4; n++)
        bfr[kk][n] = *reinterpret_cast<const bf16x8*>(
            Bb + (wn * 64 + n * 16 + fr) * 64 + (((kk * 4 + fkb) ^ key)) * 8);

    // phase 1: B-frags + A m0,m1; stage A(kt+1) h0
    GPHASE(0, if (kt + 1 < T) stage(A, m0, kt + 1, 0, 0));
    // phase 2: A m2,m3; stage A(kt+1) h1
    GPHASE(1, if (kt + 1 < T) stage(A, m0, kt + 1, 1, 0));
    // phase 3: A m4,m5; stage B(kt+2) h0
    GPHASE(2, if (kt + 2 < T) stage(B, n0, kt + 2, 0, 32768));
    // phase 4: A m6,m7; stage B(kt+2) h1; counted vmcnt
    GPHASE(3, {
      if (kt + 2 < T) {
        stage(B, n0, kt + 2, 1, 32768);
        asm volatile("s_waitcnt vmcnt(4)" ::: "memory");
      } else {
        asm volatile("s_waitcnt vmcnt(0)" ::: "memory");
      }
    });
  }
#undef GPHASE

  // ---- epilogue ----
  const int er = (l >> 4) * 4;
  const int ec = l & 15;
#pragma unroll
  for (int m = 0; m < 8; m++) {
#pragma unroll
    for (int n = 0; n < 4; n++) {
      const int col = n0 + wn * 64 + n * 16 + ec;
      if (OUT == 2) {
        const int hv = col >> 7, dh = col & 127;
        const int row0 = m0 + wm * 128 + m * 16 + er;
        const int bb = row0 >> 11;
        const int t0 = row0 & 2047;
        unsigned short* vp =
            Cb + (((size_t)(bb * 16 + hv)) * 128 + dh) * 2048 + t0;
#pragma unroll
        for (int r = 0; r < 4; r++) vp[r] = f2u(acc[m][n][r]);
      } else {
#pragma unroll
        for (int r = 0; r < 4; r++) {
          const int row = m0 + wm * 128 + m * 16 + er + r;
          if (OUT == 1) {
            Cf[(size_t)row * N + col] = acc[m][n][r] + bias[col];
          } else {
            Cb[(size_t)row * N + col] = f2u(acc[m][n][r]);
          }
        }
      }
    }
  }
}

// ---------------- flash attention (R4-verbatim: 305us known-good) ----------------
// Y2: (8192 x 4096) bf16, cols [0,2048)=Q (pre-scaled), [2048,4096)=K.
// Vtg: [64 bh][128 dh][2048 t] bf16 (V transposed per head).
// Block: 4 waves x 32 q-rows = 128 q-rows. KV tile = 64.
// K double-buffered in LDS (XOR-swizzled via pre-swizzled global source),
// V single-buffered (staged at iter top, consumed post-barrier). 2 barriers/iter.
__global__ __launch_bounds__(256, 2)
void attn_kernel(const unsigned short* __restrict__ Y2,
                 const unsigned short* __restrict__ Vtg,
                 unsigned short* __restrict__ att) {
  __shared__ unsigned short Kt[2][64 * 128];  // 2 x 16 KB, [kvrow][dh] swizzled
  __shared__ unsigned short Vt[128 * 64];     // 16 KB, [dh][kv] swizzled
  __shared__ unsigned short Pl[4][32 * 72];   // per-wave P, padded stride 72

  const int t = threadIdx.x;
  const int w = t >> 6;
  const int l = t & 63;
  const int bid = blockIdx.x;
  const int bh = bid & 63;
  const int qt = bid >> 6;  // 0..15, 128 q-rows each
  const int b = bh >> 4;
  const int h = bh & 15;

  const size_t ybase = (size_t)b * 2048 * 4096 + (size_t)h * 128;
  const unsigned short* Qp = Y2 + ybase;
  const unsigned short* Kp = Y2 + ybase + 2048;
  const unsigned short* Vp = Vtg + (size_t)bh * 128 * 2048;

  const int fr = l & 15;
  const int fkb = l >> 4;
  const int key = fr & 7;

  const int ksr = t >> 4;
  const int ksl = (t & 15) ^ (ksr & 7);
  const unsigned short* Ksrc = Kp + (size_t)ksr * 4096 + ksl * 8;

  const int vsr = t >> 3;
  const int vsl = (t & 7) ^ (vsr & 7);
  const unsigned short* Vsrc = Vp + (size_t)vsr * 2048 + vsl * 8;

  bf16x8 qf[2][4];
#pragma unroll
  for (int i = 0; i < 2; i++)
#pragma unroll
    for (int kk = 0; kk < 4; kk++)
      qf[i][kk] = *reinterpret_cast<const bf16x8*>(
          &Qp[(size_t)(qt * 128 + w * 32 + i * 16 + fr) * 4096 + kk * 32 + fkb * 8]);

  floatx4 oacc[2][8];
#pragma unroll
  for (int i = 0; i < 2; i++)
#pragma unroll
    for (int nt = 0; nt < 8; nt++) oacc[i][nt] = (floatx4){0.f, 0.f, 0.f, 0.f};
  float mrun[2][4], lrun[2][4];
#pragma unroll
  for (int i = 0; i < 2; i++)
#pragma unroll
    for (int r = 0; r < 4; r++) {
      mrun[i][r] = -INFINITY;
      lrun[i][r] = 0.f;
    }

  unsigned short* Pw = &Pl[w][0];

  // prologue: stage K(0) into Kt[0]
#pragma unroll
  for (int c = 0; c < 4; c++)
    gload_lds16(Ksrc + (size_t)c * 16 * 4096, &Kt[0][c * 2048 + w * 512]);
  __syncthreads();

  int cur = 0;
  for (int kv = 0; kv < 2048; kv += 64) {
    // ---- stage V(kv) (prev barrier guaranteed all PV reads of Vt done) ----
#pragma unroll
    for (int c = 0; c < 4; c++)
      gload_lds16(Vsrc + (size_t)c * 32 * 2048 + kv, &Vt[c * 2048 + w * 512]);

    // ---- QK^T: 32 q-rows x 64 kv from Kt[cur] ----
    floatx4 sacc[2][4];
#pragma unroll
    for (int i = 0; i < 2; i++)
#pragma unroll
      for (int nt = 0; nt < 4; nt++) sacc[i][nt] = (floatx4){0.f, 0.f, 0.f, 0.f};
#pragma unroll
    for (int nt = 0; nt < 4; nt++) {
#pragma unroll
      for (int kk = 0; kk < 4; kk++) {
        bf16x8 kf = *reinterpret_cast<const bf16x8*>(
            &Kt[cur][((nt * 16 + fr) * 16 + ((kk * 4 + fkb) ^ key)) * 8]);
        sacc[0][nt] = mfma16(qf[0][kk], kf, sacc[0][nt]);
        sacc[1][nt] = mfma16(qf[1][kk], kf, sacc[1][nt]);
      }
    }

    // ---- online softmax with defer-max (THR=8) ----
#pragma unroll
    for (int i = 0; i < 2; i++) {
#pragma unroll
      for (int r = 0; r < 4; r++) {
        float s0 = sacc[i][0][r], s1 = sacc[i][1][r];
        float s2 = sacc[i][2][r], s3 = sacc[i][3][r];
        float mx = fmaxf(fmaxf(s0, s1), fmaxf(s2, s3));
        mx = fmaxf(mx, __shfl_xor(mx, 1));
        mx = fmaxf(mx, __shfl_xor(mx, 2));
        mx = fmaxf(mx, __shfl_xor(mx, 4));
        mx = fmaxf(mx, __shfl_xor(mx, 8));
        if (mx > mrun[i][r] + 8.0f) {
          float alpha = __expf(mrun[i][r] - mx);
          mrun[i][r] = mx;
          lrun[i][r] *= alpha;
#pragma unroll
          for (int nt = 0; nt < 8; nt++) oacc[i][nt][r] *= alpha;
        }
        const float m = mrun[i][r];
        float p0 = __expf(s0 - m);
        float p1 = __expf(s1 - m);
        float p2 = __expf(s2 - m);
        float p3 = __expf(s3 - m);
        float ps = (p0 + p1) + (p2 + p3);
        ps += __shfl_xor(ps, 1);
        ps += __shfl_xor(ps, 2);
        ps += __shfl_xor(ps, 4);
        ps += __shfl_xor(ps, 8);
        lrun[i][r] += ps;
        const int pr = i * 16 + fkb * 4 + r;
        Pw[pr * 72 + fr] = f2u(p0);
        Pw[pr * 72 + 16 + fr] = f2u(p1);
        Pw[pr * 72 + 32 + fr] = f2u(p2);
        Pw[pr * 72 + 48 + fr] = f2u(p3);
      }
    }

    __syncthreads();  // V(kv) landed; Kt[cur^1] free

    // ---- stage K(kv+64) into Kt[cur^1]; latency hides under PV ----
    if (kv + 64 < 2048) {
#pragma unroll
      for (int c = 0; c < 4; c++)
        gload_lds16(Ksrc + (size_t)(kv + 64 + c * 16) * 4096,
                    &Kt[cur ^ 1][c * 2048 + w * 512]);
    }

    // ---- PV: out(32x128) += P(32x64) @ V(64x128) ----
    bf16x8 pf[2][2];
#pragma unroll
    for (int i = 0; i < 2; i++) {
      pf[i][0] = *reinterpret_cast<const bf16x8*>(&Pw[(i * 16 + fr) * 72 + fkb * 8]);
      pf[i][1] = *reinterpret_cast<const bf16x8*>(&Pw[(i * 16 + fr) * 72 + 32 + fkb * 8]);
    }
#pragma unroll
    for (int nt = 0; nt < 8; nt++) {
      const unsigned short* vr = &Vt[(nt * 16 + fr) * 64];
      bf16x8 vf0 = *reinterpret_cast<const bf16x8*>(vr + (fkb ^ key) * 8);
      bf16x8 vf1 = *reinterpret_cast<const bf16x8*>(vr + ((fkb + 4) ^ key) * 8);
#pragma unroll
      for (int i = 0; i < 2; i++) {
        oacc[i][nt] = mfma16(pf[i][0], vf0, oacc[i][nt]);
        oacc[i][nt] = mfma16(pf[i][1], vf1, oacc[i][nt]);
      }
    }

    __syncthreads();  // all Vt/Kt[cur] reads done; K(kv+64) drained
    cur ^= 1;
  }

  // ---- epilogue ----
#pragma unroll
  for (int i = 0; i < 2; i++) {
#pragma unroll
    for (int r = 0; r < 4; r++) {
      const float inv = 1.0f / lrun[i][r];
      const int row = qt * 128 + w * 32 + i * 16 + fkb * 4 + r;
      unsigned short* op = att + ((size_t)b * 2048 + row) * 2048 + h * 128 + fr;
#pragma unroll
      for (int nt = 0; nt < 8; nt++) op[nt * 16] = f2u(oacc[i][nt][r] * inv);
    }
  }
}

// ---------------- launch ----------------
extern "C" void kernel_launch(void* const* d_in, const int* in_sizes, int n_in,
                              void* d_out, int out_size, void* d_ws, size_t ws_size,
                              hipStream_t stream) {
  const float* x = (const float*)d_in[0];
  const float* wq = (const float*)d_in[1];
  const float* wk = (const float*)d_in[2];
  const float* wv = (const float*)d_in[3];
  const float* wo = (const float*)d_in[4];
  const float* bo = (const float*)d_in[5];

  unsigned short* ws = (unsigned short*)d_ws;
  unsigned short* x16 = ws;                      // 16,777,216
  unsigned short* wqkv16 = x16 + 16777216;       // 12,582,912
  unsigned short* wo16 = wqkv16 + 12582912;      // 4,194,304
  unsigned short* Y2 = wo16 + 4194304;           // 33,554,432 (8192 x 4096, Q|K)
  unsigned short* Vtg = Y2 + 33554432;           // 16,777,216 (64 x 128 x 2048)
  unsigned short* att16 = Vtg + 16777216;        // 16,777,216
  // total 100,663,296 ushorts = 201.3 MB

  const float sscale = 0.08838834764831845f;  // 1/sqrt(128), folded into wq

  // allow 128KB dynamic LDS for gemm256 (sticky attribute; not a stream op)
  hipFuncSetAttribute(reinterpret_cast<const void*>(gemm256<0>),
                      hipFuncAttributeMaxDynamicSharedMemorySize, 131072);
  hipFuncSetAttribute(reinterpret_cast<const void*>(gemm256<1>),
                      hipFuncAttributeMaxDynamicSharedMemorySize, 131072);
  hipFuncSetAttribute(reinterpret_cast<const void*>(gemm256<2>),
                      hipFuncAttributeMaxDynamicSharedMemorySize, 131072);

  castk<<<16384, 256, 0, stream>>>(x, x16, 4194304, 1.0f);
  castk<<<4096, 256, 0, stream>>>(wq, wqkv16, 1048576, sscale);
  castk<<<4096, 256, 0, stream>>>(wk, wqkv16 + 4194304, 1048576, 1.0f);
  castk<<<4096, 256, 0, stream>>>(wv, wqkv16 + 8388608, 1048576, 1.0f);
  castk<<<4096, 256, 0, stream>>>(wo, wo16, 1048576, 1.0f);

  // Q,K projections -> Y2 (row-major)
  dim3 gqk(16, 32);
  gemm256<0><<<gqk, 512, 131072, stream>>>(x16, wqkv16, Y2, nullptr, nullptr,
                                           8192, 4096, 2048);
  // V projection -> Vtg (transposed per head)
  dim3 gv(8, 32);
  gemm256<2><<<gv, 512, 131072, stream>>>(x16, wqkv16 + 8388608, Vtg, nullptr,
                                          nullptr, 8192, 2048, 2048);

  attn_kernel<<<1024, 256, 0, stream>>>(Y2, Vtg, att16);

  dim3 go(8, 32);
  gemm256<1><<<go, 512, 131072, stream>>>(att16, wo16, nullptr, (float*)d_out,
                                          bo, 8192, 2048, 2048);
}

// Round 7
// 541.957 us; speedup vs baseline: 1.5263x; 1.0274x over previous
//
#include <hip/hip_runtime.h>
#include <hip/hip_bf16.h>
#include <math.h>

typedef __attribute__((ext_vector_type(8))) __bf16 bf16x8;
typedef __attribute__((ext_vector_type(4))) float floatx4;

__device__ inline unsigned short f2u(float f) {
  __hip_bfloat16 h = __float2bfloat16(f);
  unsigned short u;
  __builtin_memcpy(&u, &h, 2);
  return u;
}

__device__ inline floatx4 mfma16(bf16x8 a, bf16x8 b, floatx4 c) {
  return __builtin_amdgcn_mfma_f32_16x16x32_bf16(a, b, c, 0, 0, 0);
}

__device__ inline void gload_lds16(const unsigned short* g, unsigned short* l) {
  __builtin_amdgcn_global_load_lds(
      (__attribute__((address_space(1))) void*)g,
      (__attribute__((address_space(3))) void*)l,
      16, 0, 0);
}

// ---------------- cast fp32 -> bf16 (vectorized, optional scale) ----------------
__global__ __launch_bounds__(256) void castk(const float* __restrict__ in,
                                             unsigned short* __restrict__ out,
                                             int n4, float scale) {
  int i = blockIdx.x * 256 + threadIdx.x;
  if (i >= n4) return;
  const float4 v = reinterpret_cast<const float4*>(in)[i];
  ushort4 o;
  o.x = f2u(v.x * scale);
  o.y = f2u(v.y * scale);
  o.z = f2u(v.z * scale);
  o.w = f2u(v.w * scale);
  reinterpret_cast<ushort4*>(out)[i] = o;
}

// fused cast of the 4 weight matrices (each 1,048,576 float4), wq scaled
__global__ __launch_bounds__(256) void castw4(const float* __restrict__ wq,
                                              const float* __restrict__ wk,
                                              const float* __restrict__ wv,
                                              const float* __restrict__ wo,
                                              unsigned short* __restrict__ oq,
                                              unsigned short* __restrict__ ok,
                                              unsigned short* __restrict__ ov,
                                              unsigned short* __restrict__ oo,
                                              float qscale) {
  const int tensor = blockIdx.x >> 12;          // 4096 blocks per tensor
  const int i = (blockIdx.x & 4095) * 256 + threadIdx.x;
  const float* in = tensor == 0 ? wq : tensor == 1 ? wk : tensor == 2 ? wv : wo;
  unsigned short* out = tensor == 0 ? oq : tensor == 1 ? ok : tensor == 2 ? ov : oo;
  const float s = tensor == 0 ? qscale : 1.0f;
  const float4 v = reinterpret_cast<const float4*>(in)[i];
  ushort4 o;
  o.x = f2u(v.x * s);
  o.y = f2u(v.y * s);
  o.z = f2u(v.z * s);
  o.w = f2u(v.w * s);
  reinterpret_cast<ushort4*>(out)[i] = o;
}

// ---------------- 256x256 8-phase GEMM: C[m,n] = sum_k A[m,k]*B[n,k] ----------
// 8 waves (2M x 4N), BK=64, 128KB dynamic LDS (A dbuf 64KB + B dbuf 64KB),
// 4 phases/K-tile, counted vmcnt(4) once per tile, raw s_barrier, setprio.
// OUT: 0 = bf16 row-major, 1 = f32 + bias, 2 = bf16 V-transposed.
template <int OUT>
__global__ __launch_bounds__(512, 2)
void gemm256(const unsigned short* __restrict__ A,
             const unsigned short* __restrict__ B,
             unsigned short* __restrict__ Cb,
             float* __restrict__ Cf,
             const float* __restrict__ bias,
             int M, int N, int K) {
  extern __shared__ unsigned short lds[];
  const int t = threadIdx.x;
  const int w = t >> 6;
  const int l = t & 63;
  const int wm = w >> 2;
  const int wn = w & 3;
  const int fr = l & 15;
  const int fkb = l >> 4;
  const int key = fr & 7;
  const int sslot = (l & 7) ^ (l >> 3);

  const int m0 = blockIdx.y * 256;
  const int n0 = blockIdx.x * 256;
  const int T = K >> 6;

  auto stage = [&](const unsigned short* G, int rb, int kt2, int h, int ldsbase) {
    const int d2 = kt2 & 1;
    const int rt = h * 128 + w * 16 + (l >> 3);
    const unsigned short* s0 = G + (size_t)(rb + rt) * K + kt2 * 64 + sslot * 8;
    unsigned short* dst = lds + ldsbase + d2 * 16384 + h * 8192 + w * 1024;
    gload_lds16(s0, dst);
    gload_lds16(s0 + (size_t)8 * K, dst + 512);
  };

  floatx4 acc[8][4];
#pragma unroll
  for (int m = 0; m < 8; m++)
#pragma unroll
    for (int n = 0; n < 4; n++) acc[m][n] = (floatx4){0.f, 0.f, 0.f, 0.f};

  stage(A, m0, 0, 0, 0);
  stage(A, m0, 0, 1, 0);
  stage(B, n0, 0, 0, 32768);
  stage(B, n0, 0, 1, 32768);
  if (1 < T) {
    stage(B, n0, 1, 0, 32768);
    stage(B, n0, 1, 1, 32768);
    asm volatile("s_waitcnt vmcnt(4)" ::: "memory");
  } else {
    asm volatile("s_waitcnt vmcnt(0)" ::: "memory");
  }
  __builtin_amdgcn_s_barrier();

#define GPHASE(q, STAGE_STMT)                                               \
  {                                                                         \
    bf16x8 a00 = *reinterpret_cast<const bf16x8*>(                          \
        Ab + (wm * 128 + (2 * (q)) * 16 + fr) * 64 + ((fkb ^ key)) * 8);    \
    bf16x8 a01 = *reinterpret_cast<const bf16x8*>(                          \
        Ab + (wm * 128 + (2 * (q)) * 16 + fr) * 64 + (((4 + fkb) ^ key)) * 8); \
    bf16x8 a10 = *reinterpret_cast<const bf16x8*>(                          \
        Ab + (wm * 128 + (2 * (q) + 1) * 16 + fr) * 64 + ((fkb ^ key)) * 8);\
    bf16x8 a11 = *reinterpret_cast<const bf16x8*>(                          \
        Ab + (wm * 128 + (2 * (q) + 1) * 16 + fr) * 64 + (((4 + fkb) ^ key)) * 8); \
    STAGE_STMT;                                                             \
    __builtin_amdgcn_s_barrier();                                           \
    asm volatile("s_waitcnt lgkmcnt(0)");                                   \
    __builtin_amdgcn_s_setprio(1);                                          \
    _Pragma("unroll")                                                       \
    for (int n = 0; n < 4; n++) {                                           \
      acc[2 * (q)][n] = mfma16(a00, bfr[0][n], acc[2 * (q)][n]);            \
      acc[2 * (q)][n] = mfma16(a01, bfr[1][n], acc[2 * (q)][n]);            \
      acc[2 * (q) + 1][n] = mfma16(a10, bfr[0][n], acc[2 * (q) + 1][n]);    \
      acc[2 * (q) + 1][n] = mfma16(a11, bfr[1][n], acc[2 * (q) + 1][n]);    \
    }                                                                       \
    __builtin_amdgcn_s_setprio(0);                                          \
    __builtin_amdgcn_s_barrier();                                           \
  }

  for (int kt = 0; kt < T; ++kt) {
    const int d = kt & 1;
    const unsigned short* Ab = lds + d * 16384;
    const unsigned short* Bb = lds + 32768 + d * 16384;

    bf16x8 bfr[2][4];
#pragma unroll
    for (int kk = 0; kk < 2; kk++)
#pragma unroll
      for (int n = 0; n < 4; n++)
        bfr[kk][n] = *reinterpret_cast<const bf16x8*>(
            Bb + (wn * 64 + n * 16 + fr) * 64 + (((kk * 4 + fkb) ^ key)) * 8);

    GPHASE(0, if (kt + 1 < T) stage(A, m0, kt + 1, 0, 0));
    GPHASE(1, if (kt + 1 < T) stage(A, m0, kt + 1, 1, 0));
    GPHASE(2, if (kt + 2 < T) stage(B, n0, kt + 2, 0, 32768));
    GPHASE(3, {
      if (kt + 2 < T) {
        stage(B, n0, kt + 2, 1, 32768);
        asm volatile("s_waitcnt vmcnt(4)" ::: "memory");
      } else {
        asm volatile("s_waitcnt vmcnt(0)" ::: "memory");
      }
    });
  }
#undef GPHASE

  const int er = (l >> 4) * 4;
  const int ec = l & 15;
#pragma unroll
  for (int m = 0; m < 8; m++) {
#pragma unroll
    for (int n = 0; n < 4; n++) {
      const int col = n0 + wn * 64 + n * 16 + ec;
      if (OUT == 2) {
        const int hv = col >> 7, dh = col & 127;
        const int row0 = m0 + wm * 128 + m * 16 + er;
        const int bb = row0 >> 11;
        const int t0 = row0 & 2047;
        unsigned short* vp =
            Cb + (((size_t)(bb * 16 + hv)) * 128 + dh) * 2048 + t0;
#pragma unroll
        for (int r = 0; r < 4; r++) vp[r] = f2u(acc[m][n][r]);
      } else {
#pragma unroll
        for (int r = 0; r < 4; r++) {
          const int row = m0 + wm * 128 + m * 16 + er + r;
          if (OUT == 1) {
            Cf[(size_t)row * N + col] = acc[m][n][r] + bias[col];
          } else {
            Cb[(size_t)row * N + col] = f2u(acc[m][n][r]);
          }
        }
      }
    }
  }
}

// ---------------- flash attention ----------------
// R4 structure with K SINGLE-buffered: LDS 50KB -> 3 blocks/CU (12 waves/CU).
// launch_bounds(256,2) keeps the compiler's natural VGPR (~104, no spill);
// runtime occupancy is LDS-limited to 3 blocks. No setprio (m190).
// Order: QK^T -> softmax -> bar1 -> stage K(next) -> PV -> bar2 -> stage V(next).
__global__ __launch_bounds__(256, 2)
void attn_kernel(const unsigned short* __restrict__ Y2,
                 const unsigned short* __restrict__ Vtg,
                 unsigned short* __restrict__ att) {
  __shared__ unsigned short Kt[64 * 128];   // 16 KB, [kvrow][dh] swizzled
  __shared__ unsigned short Vt[128 * 64];   // 16 KB, [dh][kv] swizzled
  __shared__ unsigned short Pl[4][32 * 72]; // 18 KB, per-wave P, stride 72

  const int t = threadIdx.x;
  const int w = t >> 6;
  const int l = t & 63;
  const int bid = blockIdx.x;
  const int bh = bid & 63;
  const int qt = bid >> 6;  // 0..15, 128 q-rows each
  const int b = bh >> 4;
  const int h = bh & 15;

  const size_t ybase = (size_t)b * 2048 * 4096 + (size_t)h * 128;
  const unsigned short* Qp = Y2 + ybase;
  const unsigned short* Kp = Y2 + ybase + 2048;
  const unsigned short* Vp = Vtg + (size_t)bh * 128 * 2048;

  const int fr = l & 15;
  const int fkb = l >> 4;
  const int key = fr & 7;

  const int ksr = t >> 4;
  const int ksl = (t & 15) ^ (ksr & 7);
  const unsigned short* Ksrc = Kp + (size_t)ksr * 4096 + ksl * 8;

  const int vsr = t >> 3;
  const int vsl = (t & 7) ^ (vsr & 7);
  const unsigned short* Vsrc = Vp + (size_t)vsr * 2048 + vsl * 8;

  bf16x8 qf[2][4];
#pragma unroll
  for (int i = 0; i < 2; i++)
#pragma unroll
    for (int kk = 0; kk < 4; kk++)
      qf[i][kk] = *reinterpret_cast<const bf16x8*>(
          &Qp[(size_t)(qt * 128 + w * 32 + i * 16 + fr) * 4096 + kk * 32 + fkb * 8]);

  floatx4 oacc[2][8];
#pragma unroll
  for (int i = 0; i < 2; i++)
#pragma unroll
    for (int nt = 0; nt < 8; nt++) oacc[i][nt] = (floatx4){0.f, 0.f, 0.f, 0.f};
  float mrun[2][4], lrun[2][4];
#pragma unroll
  for (int i = 0; i < 2; i++)
#pragma unroll
    for (int r = 0; r < 4; r++) {
      mrun[i][r] = -INFINITY;
      lrun[i][r] = 0.f;
    }

  unsigned short* Pw = &Pl[w][0];

  // prologue: stage K(0), V(0)
#pragma unroll
  for (int c = 0; c < 4; c++)
    gload_lds16(Ksrc + (size_t)c * 16 * 4096, &Kt[c * 2048 + w * 512]);
#pragma unroll
  for (int c = 0; c < 4; c++)
    gload_lds16(Vsrc + (size_t)c * 32 * 2048, &Vt[c * 2048 + w * 512]);
  __syncthreads();  // vmcnt drained: K(0), V(0) ready

  for (int kv = 0; kv < 2048; kv += 64) {
    // ---- QK^T: 32 q-rows x 64 kv from Kt ----
    floatx4 sacc[2][4];
#pragma unroll
    for (int i = 0; i < 2; i++)
#pragma unroll
      for (int nt = 0; nt < 4; nt++) sacc[i][nt] = (floatx4){0.f, 0.f, 0.f, 0.f};
#pragma unroll
    for (int nt = 0; nt < 4; nt++) {
#pragma unroll
      for (int kk = 0; kk < 4; kk++) {
        bf16x8 kf = *reinterpret_cast<const bf16x8*>(
            &Kt[((nt * 16 + fr) * 16 + ((kk * 4 + fkb) ^ key)) * 8]);
        sacc[0][nt] = mfma16(qf[0][kk], kf, sacc[0][nt]);
        sacc[1][nt] = mfma16(qf[1][kk], kf, sacc[1][nt]);
      }
    }

    // ---- online softmax with defer-max (THR=8) ----
#pragma unroll
    for (int i = 0; i < 2; i++) {
#pragma unroll
      for (int r = 0; r < 4; r++) {
        float s0 = sacc[i][0][r], s1 = sacc[i][1][r];
        float s2 = sacc[i][2][r], s3 = sacc[i][3][r];
        float mx = fmaxf(fmaxf(s0, s1), fmaxf(s2, s3));
        mx = fmaxf(mx, __shfl_xor(mx, 1));
        mx = fmaxf(mx, __shfl_xor(mx, 2));
        mx = fmaxf(mx, __shfl_xor(mx, 4));
        mx = fmaxf(mx, __shfl_xor(mx, 8));
        if (mx > mrun[i][r] + 8.0f) {
          float alpha = __expf(mrun[i][r] - mx);
          mrun[i][r] = mx;
          lrun[i][r] *= alpha;
#pragma unroll
          for (int nt = 0; nt < 8; nt++) oacc[i][nt][r] *= alpha;
        }
        const float m = mrun[i][r];
        float p0 = __expf(s0 - m);
        float p1 = __expf(s1 - m);
        float p2 = __expf(s2 - m);
        float p3 = __expf(s3 - m);
        float ps = (p0 + p1) + (p2 + p3);
        ps += __shfl_xor(ps, 1);
        ps += __shfl_xor(ps, 2);
        ps += __shfl_xor(ps, 4);
        ps += __shfl_xor(ps, 8);
        lrun[i][r] += ps;
        const int pr = i * 16 + fkb * 4 + r;
        Pw[pr * 72 + fr] = f2u(p0);
        Pw[pr * 72 + 16 + fr] = f2u(p1);
        Pw[pr * 72 + 32 + fr] = f2u(p2);
        Pw[pr * 72 + 48 + fr] = f2u(p3);
      }
    }

    __syncthreads();  // bar1: all Kt reads done; prior V-stage drained

    // ---- stage K(kv+64) into Kt; latency hides under PV ----
    if (kv + 64 < 2048) {
#pragma unroll
      for (int c = 0; c < 4; c++)
        gload_lds16(Ksrc + (size_t)(kv + 64 + c * 16) * 4096,
                    &Kt[c * 2048 + w * 512]);
    }

    // ---- PV: out(32x128) += P(32x64) @ V(64x128) ----
    bf16x8 pf[2][2];
#pragma unroll
    for (int i = 0; i < 2; i++) {
      pf[i][0] = *reinterpret_cast<const bf16x8*>(&Pw[(i * 16 + fr) * 72 + fkb * 8]);
      pf[i][1] = *reinterpret_cast<const bf16x8*>(&Pw[(i * 16 + fr) * 72 + 32 + fkb * 8]);
    }
#pragma unroll
    for (int nt = 0; nt < 8; nt++) {
      const unsigned short* vr = &Vt[(nt * 16 + fr) * 64];
      bf16x8 vf0 = *reinterpret_cast<const bf16x8*>(vr + (fkb ^ key) * 8);
      bf16x8 vf1 = *reinterpret_cast<const bf16x8*>(vr + ((fkb + 4) ^ key) * 8);
#pragma unroll
      for (int i = 0; i < 2; i++) {
        oacc[i][nt] = mfma16(pf[i][0], vf0, oacc[i][nt]);
        oacc[i][nt] = mfma16(pf[i][1], vf1, oacc[i][nt]);
      }
    }

    __syncthreads();  // bar2: all Vt reads done; K(kv+64) drained

    // ---- stage V(kv+64) into Vt; latency hides under next QK^T+softmax ----
    if (kv + 64 < 2048) {
#pragma unroll
      for (int c = 0; c < 4; c++)
        gload_lds16(Vsrc + (size_t)c * 32 * 2048 + (kv + 64),
                    &Vt[c * 2048 + w * 512]);
    }
  }

  // ---- epilogue ----
#pragma unroll
  for (int i = 0; i < 2; i++) {
#pragma unroll
    for (int r = 0; r < 4; r++) {
      const float inv = 1.0f / lrun[i][r];
      const int row = qt * 128 + w * 32 + i * 16 + fkb * 4 + r;
      unsigned short* op = att + ((size_t)b * 2048 + row) * 2048 + h * 128 + fr;
#pragma unroll
      for (int nt = 0; nt < 8; nt++) op[nt * 16] = f2u(oacc[i][nt][r] * inv);
    }
  }
}

// ---------------- launch ----------------
extern "C" void kernel_launch(void* const* d_in, const int* in_sizes, int n_in,
                              void* d_out, int out_size, void* d_ws, size_t ws_size,
                              hipStream_t stream) {
  const float* x = (const float*)d_in[0];
  const float* wq = (const float*)d_in[1];
  const float* wk = (const float*)d_in[2];
  const float* wv = (const float*)d_in[3];
  const float* wo = (const float*)d_in[4];
  const float* bo = (const float*)d_in[5];

  unsigned short* ws = (unsigned short*)d_ws;
  unsigned short* x16 = ws;                      // 16,777,216
  unsigned short* wqkv16 = x16 + 16777216;       // 12,582,912
  unsigned short* wo16 = wqkv16 + 12582912;      // 4,194,304
  unsigned short* Y2 = wo16 + 4194304;           // 33,554,432 (8192 x 4096, Q|K)
  unsigned short* Vtg = Y2 + 33554432;           // 16,777,216 (64 x 128 x 2048)
  unsigned short* att16 = Vtg + 16777216;        // 16,777,216
  // total 100,663,296 ushorts = 201.3 MB

  const float sscale = 0.08838834764831845f;  // 1/sqrt(128), folded into wq

  hipFuncSetAttribute(reinterpret_cast<const void*>(gemm256<0>),
                      hipFuncAttributeMaxDynamicSharedMemorySize, 131072);
  hipFuncSetAttribute(reinterpret_cast<const void*>(gemm256<1>),
                      hipFuncAttributeMaxDynamicSharedMemorySize, 131072);
  hipFuncSetAttribute(reinterpret_cast<const void*>(gemm256<2>),
                      hipFuncAttributeMaxDynamicSharedMemorySize, 131072);

  castk<<<16384, 256, 0, stream>>>(x, x16, 4194304, 1.0f);
  castw4<<<16384, 256, 0, stream>>>(wq, wk, wv, wo,
                                    wqkv16, wqkv16 + 4194304,
                                    wqkv16 + 8388608, wo16, sscale);

  // Q,K projections -> Y2 (row-major)
  dim3 gqk(16, 32);
  gemm256<0><<<gqk, 512, 131072, stream>>>(x16, wqkv16, Y2, nullptr, nullptr,
                                           8192, 4096, 2048);
  // V projection -> Vtg (transposed per head)
  dim3 gv(8, 32);
  gemm256<2><<<gv, 512, 131072, stream>>>(x16, wqkv16 + 8388608, Vtg, nullptr,
                                          nullptr, 8192, 2048, 2048);

  attn_kernel<<<1024, 256, 0, stream>>>(Y2, Vtg, att16);

  dim3 go(8, 32);
  gemm256<1><<<go, 512, 131072, stream>>>(att16, wo16, nullptr, (float*)d_out,
                                          bo, 8192, 2048, 2048);
}